// Round 2
// baseline (10252.271 us; speedup 1.0000x reference)
//
#include <hip/hip_runtime.h>
#include <hip/hip_bf16.h>

// N=128, T=128, D=1024, H=1024, 4H=4096, K = H(h) + H(attn) + D(x) = 3072
// Reordered output col c = 4*unit + gate  <->  orig col j = gate*1024 + unit.
// K rows ordered [Wh | Wattn | Wx] matching act = [h | attn | x].

typedef __bf16 bf16x8 __attribute__((ext_vector_type(8)));
typedef float f32x4 __attribute__((ext_vector_type(4)));

__device__ __forceinline__ unsigned short f2bf(float f) {
    unsigned int u = __float_as_uint(f);
    u += 0x7FFFu + ((u >> 16) & 1u);   // round-to-nearest-even
    return (unsigned short)(u >> 16);
}
__device__ __forceinline__ float sigf(float x) { return 1.0f / (1.0f + expf(-x)); }

// ---------------------------------------------------------------------------
// Fragment-linear weight image. Slice s (0..127) covers reordered cols
// [32s, 32s+32). Slot (s, ks, cf, l) holds bf16 W[k0..k0+8)[j(col)] with
//   col = 32s + 16cf + (l&15),  k0 = 32ks + 8*(l>>4),  ks in [0,96).
// A wave's B-fragment load is then 64 lanes x 16B contiguous.
// ---------------------------------------------------------------------------
__global__ __launch_bounds__(256) void k_build_wtf(
    const float* __restrict__ Wx, const float* __restrict__ Wh,
    const float* __restrict__ Wattn, unsigned short* __restrict__ WTf) {
    const int slot = blockIdx.x * 256 + threadIdx.x;   // 128*96*2*64 slots
    const int l  = slot & 63;
    const int r1 = slot >> 6;
    const int cf = r1 & 1;
    const int r2 = r1 >> 1;
    const int ks = r2 % 96;
    const int s  = r2 / 96;
    const int col = s * 32 + cf * 16 + (l & 15);
    const int g = col & 3, u = col >> 2;
    const int j = g * 1024 + u;
    const int k0 = ks * 32 + ((l >> 4) << 3);          // stays in one region
    unsigned short v[8];
#pragma unroll
    for (int i = 0; i < 8; ++i) {
        const int k = k0 + i;
        float w;
        if (k < 1024)      w = Wh[(size_t)k * 4096 + j];
        else if (k < 2048) w = Wattn[(size_t)(k - 1024) * 4096 + j];
        else               w = Wx[(size_t)(k - 2048) * 4096 + j];
        v[i] = f2bf(w);
    }
    *(int4*)&WTf[(size_t)slot * 8] = *(const int4*)v;
}

// ---------------------------------------------------------------------------
// h0 = c0 = mean over the 16 spatial positions of A; seed act0 h-part.
// ---------------------------------------------------------------------------
__global__ __launch_bounds__(256) void k_init(
    const float* __restrict__ A, float* __restrict__ h, float* __restrict__ c,
    unsigned short* __restrict__ act0) {
    int idx = blockIdx.x * 256 + threadIdx.x;     // n*1024+u
    const float4* ap = (const float4*)(A + (size_t)idx * 16);
    float4 a0 = ap[0], a1 = ap[1], a2 = ap[2], a3 = ap[3];
    float s = a0.x + a0.y + a0.z + a0.w + a1.x + a1.y + a1.z + a1.w +
              a2.x + a2.y + a2.z + a2.w + a3.x + a3.y + a3.z + a3.w;
    float h0 = s * (1.0f / 16.0f);
    h[idx] = h0;
    c[idx] = h0;
    int n = idx >> 10, u = idx & 1023;
    act0[n * 3072 + u] = f2bf(h0);
}

// ---------------------------------------------------------------------------
// Per-step attention (f32) + pack act = [h | attn | x_t] (bf16). Block per n.
// ---------------------------------------------------------------------------
__global__ __launch_bounds__(256) void k_attn(
    const float* __restrict__ A, const float* __restrict__ h,
    const float* __restrict__ x, unsigned short* __restrict__ act, int t) {
    __shared__ float red[16][4];
    __shared__ float wsm[16];
    const int n = blockIdx.x;
    const int tid = threadIdx.x;
    const int lane = tid & 63, wave = tid >> 6;

    const float4 hv = *(const float4*)&h[n * 1024 + tid * 4];
    float hvj[4] = {hv.x, hv.y, hv.z, hv.w};
    float part[16];
#pragma unroll
    for (int p = 0; p < 16; ++p) part[p] = 0.0f;
#pragma unroll
    for (int j = 0; j < 4; ++j) {
        const float4* ar = (const float4*)&A[((size_t)n * 1024 + tid * 4 + j) * 16];
        float4 a0 = ar[0], a1 = ar[1], a2 = ar[2], a3 = ar[3];
        float hh = hvj[j];
        part[0] += hh * a0.x;  part[1] += hh * a0.y;  part[2] += hh * a0.z;  part[3] += hh * a0.w;
        part[4] += hh * a1.x;  part[5] += hh * a1.y;  part[6] += hh * a1.z;  part[7] += hh * a1.w;
        part[8] += hh * a2.x;  part[9] += hh * a2.y;  part[10] += hh * a2.z; part[11] += hh * a2.w;
        part[12] += hh * a3.x; part[13] += hh * a3.y; part[14] += hh * a3.z; part[15] += hh * a3.w;
    }
#pragma unroll
    for (int off = 32; off >= 1; off >>= 1) {
#pragma unroll
        for (int p = 0; p < 16; ++p) part[p] += __shfl_down(part[p], off);
    }
    if (lane == 0) {
#pragma unroll
        for (int p = 0; p < 16; ++p) red[p][wave] = part[p];
    }
    __syncthreads();
    if (tid == 0) {
        float sc[16], mx = -1e30f;
#pragma unroll
        for (int p = 0; p < 16; ++p) {
            sc[p] = (red[p][0] + red[p][1] + red[p][2] + red[p][3]) * 0.03125f;
            mx = fmaxf(mx, sc[p]);
        }
        float se = 0.0f;
#pragma unroll
        for (int p = 0; p < 16; ++p) { sc[p] = expf(sc[p] - mx); se += sc[p]; }
        float inv = 1.0f / se;
#pragma unroll
        for (int p = 0; p < 16; ++p) wsm[p] = sc[p] * inv;
    }
    __syncthreads();
    float w[16];
#pragma unroll
    for (int p = 0; p < 16; ++p) w[p] = wsm[p];

    unsigned short pk[4];
#pragma unroll
    for (int j = 0; j < 4; ++j) {
        const float4* ar = (const float4*)&A[((size_t)n * 1024 + tid * 4 + j) * 16];
        float4 a0 = ar[0], a1 = ar[1], a2 = ar[2], a3 = ar[3];
        float av = w[0] * a0.x + w[1] * a0.y + w[2] * a0.z + w[3] * a0.w +
                   w[4] * a1.x + w[5] * a1.y + w[6] * a1.z + w[7] * a1.w +
                   w[8] * a2.x + w[9] * a2.y + w[10] * a2.z + w[11] * a2.w +
                   w[12] * a3.x + w[13] * a3.y + w[14] * a3.z + w[15] * a3.w;
        pk[j] = f2bf(av);
    }
    *(ushort4*)&act[n * 3072 + 1024 + tid * 4] = make_ushort4(pk[0], pk[1], pk[2], pk[3]);

    const float4 xv = *(const float4*)&x[((size_t)n * 128 + t) * 1024 + tid * 4];
    *(ushort4*)&act[n * 3072 + 2048 + tid * 4] =
        make_ushort4(f2bf(xv.x), f2bf(xv.y), f2bf(xv.z), f2bf(xv.w));
}

// ---------------------------------------------------------------------------
// Per-step fused GEMM + LSTM cell update, barrier-light.
// 64 blocks x 512 threads (8 waves). Block: all 128 rows x 64 reordered cols,
// K=3072. Wave (rg=w>>1, cg=w&1): 32 rows x 32 cols = 2x2 fragments.
// A-fragments streamed directly from global act (L2-resident, no LDS).
// B-fragments double-buffered in LDS, staged from fragment-linear WTf in
// 128-K chunks (issue-early / write-late; ONE barrier per chunk).
// Epilogue: 4-lane shfl_xor gathers the 4 gates of a unit; writes c,h f32,
// bf16 h into actout, and out[n][t][u].
// ---------------------------------------------------------------------------
__global__ __launch_bounds__(512) void k_gemm(
    const unsigned short* __restrict__ WTf, const unsigned short* __restrict__ actin,
    unsigned short* __restrict__ actout, const float* __restrict__ b,
    float* __restrict__ h, float* __restrict__ c, float* __restrict__ out, int t) {
    __shared__ unsigned short Bs[2][4 * 4 * 64 * 8];   // 2 x 16 KiB
    const int tid = threadIdx.x;
    const int lane = tid & 63, wave = tid >> 6;        // 8 waves
    const int rg = wave >> 1, cg = wave & 1;
    const int cbase = blockIdx.x * 64;

    // staging slot for this thread: slot i -> (ksl, cfi, l)
    const int sl_l   = tid & 63;
    const int sl_r0  = tid >> 6;        // 0..7  -> first  slot rest index
    // second slot: rest index + 8  (512 threads cover 1024 int4 slots)

    f32x4 acc[2][2] = {};

    // ---- stage chunk 0 ----
    {
#pragma unroll
        for (int i = 0; i < 2; ++i) {
            const int rest = sl_r0 + i * 8;            // ksl*4 + cfi, 0..15
            const int cfi = rest & 3, ksl = rest >> 2;
            const int s = blockIdx.x * 2 + (cfi >> 1);
            const int cf = cfi & 1;
            const int ksg = 0 * 4 + ksl;
            const int4 v = *(const int4*)&WTf[(((size_t)s * 192 + (size_t)ksg * 2 + cf) * 64 + sl_l) * 8];
            *(int4*)&Bs[0][((size_t)rest * 64 + sl_l) * 8] = v;
        }
    }
    __syncthreads();

    int cur = 0;
    for (int ch = 0; ch < 24; ++ch) {
        // issue next chunk's global loads early
        int4 r0, r1;
        const bool pf = (ch + 1 < 24);
        if (pf) {
#pragma unroll
            for (int i = 0; i < 2; ++i) {
                const int rest = sl_r0 + i * 8;
                const int cfi = rest & 3, ksl = rest >> 2;
                const int s = blockIdx.x * 2 + (cfi >> 1);
                const int cf = cfi & 1;
                const int ksg = (ch + 1) * 4 + ksl;
                const int4 v = *(const int4*)&WTf[(((size_t)s * 192 + (size_t)ksg * 2 + cf) * 64 + sl_l) * 8];
                if (i == 0) r0 = v; else r1 = v;
            }
        }
        // compute current chunk
#pragma unroll
        for (int ksl = 0; ksl < 4; ++ksl) {
            const int k = ch * 128 + ksl * 32 + ((lane >> 4) << 3);
            const int ra = rg * 32 + (lane & 15);
            bf16x8 a0 = *(const bf16x8*)&actin[ra * 3072 + k];
            bf16x8 a1 = *(const bf16x8*)&actin[(ra + 16) * 3072 + k];
            const int f0 = (ksl * 4 + cg * 2) * 64 + lane;
            bf16x8 b0 = *(const bf16x8*)&Bs[cur][(size_t)f0 * 8];
            bf16x8 b1 = *(const bf16x8*)&Bs[cur][((size_t)f0 + 64) * 8];
            acc[0][0] = __builtin_amdgcn_mfma_f32_16x16x32_bf16(a0, b0, acc[0][0], 0, 0, 0);
            acc[0][1] = __builtin_amdgcn_mfma_f32_16x16x32_bf16(a0, b1, acc[0][1], 0, 0, 0);
            acc[1][0] = __builtin_amdgcn_mfma_f32_16x16x32_bf16(a1, b0, acc[1][0], 0, 0, 0);
            acc[1][1] = __builtin_amdgcn_mfma_f32_16x16x32_bf16(a1, b1, acc[1][1], 0, 0, 0);
        }
        // write-late into the other buffer
        if (pf) {
            *(int4*)&Bs[cur ^ 1][((size_t)(sl_r0 + 0) * 64 + sl_l) * 8] = r0;
            *(int4*)&Bs[cur ^ 1][((size_t)(sl_r0 + 8) * 64 + sl_l) * 8] = r1;
        }
        __syncthreads();
        cur ^= 1;
    }

    // ---- epilogue: gates + state update ----
#pragma unroll
    for (int cf = 0; cf < 2; ++cf) {
        const int cfi = cg * 2 + cf;
        const int col = cbase + cfi * 16 + (lane & 15);   // reordered col = 4u+g
        const int u = col >> 2, g = col & 3;
        const float bias = b[g * 1024 + u];
#pragma unroll
        for (int rf = 0; rf < 2; ++rf) {
#pragma unroll
            for (int reg = 0; reg < 4; ++reg) {
                const int r = rg * 32 + rf * 16 + ((lane >> 4) << 2) + reg;
                float a = acc[rf][cf][reg] + bias;
                float v1 = __shfl_xor(a, 1);
                float v2 = __shfl_xor(a, 2);
                float v3 = __shfl_xor(a, 3);
                // value of gate X for this unit lives on lane l^(g^X)
                auto pick = [&](int m) { return m == 0 ? a : m == 1 ? v1 : m == 2 ? v2 : v3; };
                float ii = sigf(pick(g));
                float ff = sigf(pick(g ^ 1));
                float oo = sigf(pick(g ^ 2));
                float gg = tanhf(pick(g ^ 3));
                const float cold = c[r * 1024 + u];
                const float nc = ff * cold + ii * gg;
                const float nh = oo * tanhf(nc);
                if (g == 0)      c[r * 1024 + u] = nc;
                else if (g == 1) h[r * 1024 + u] = nh;
                else if (g == 2) actout[r * 3072 + u] = f2bf(nh);
                else             out[((size_t)r * 128 + t) * 1024 + u] = nh;
            }
        }
    }
}

extern "C" void kernel_launch(void* const* d_in, const int* in_sizes, int n_in,
                              void* d_out, int out_size, void* d_ws, size_t ws_size,
                              hipStream_t stream) {
    const float* x     = (const float*)d_in[0];   // (128,128,1024)
    const float* A     = (const float*)d_in[1];   // (128,1024,4,4)
    const float* Wx    = (const float*)d_in[2];   // (1024,4096)
    const float* Wh    = (const float*)d_in[3];   // (1024,4096)
    const float* Wattn = (const float*)d_in[4];   // (1024,4096)
    const float* b     = (const float*)d_in[5];   // (4096,)
    float* out = (float*)d_out;                   // (128,128,1024) f32

    char* ws = (char*)d_ws;
    // ws layout (~26.5 MB)
    unsigned short* WTf  = (unsigned short*)(ws);                    // 24 MB
    unsigned short* act0 = (unsigned short*)(ws + 25165824);         // 768 KB
    unsigned short* act1 = (unsigned short*)(ws + 25952256);         // 768 KB
    float* h = (float*)(ws + 26738688);                              // 512 KB
    float* c = (float*)(ws + 27262976);                              // 512 KB

    k_build_wtf<<<6144, 256, 0, stream>>>(Wx, Wh, Wattn, WTf);
    k_init<<<512, 256, 0, stream>>>(A, h, c, act0);
    for (int t = 0; t < 128; ++t) {
        unsigned short* ain  = (t & 1) ? act1 : act0;
        unsigned short* aout = (t & 1) ? act0 : act1;
        k_attn<<<128, 256, 0, stream>>>(A, h, x, ain, t);
        k_gemm<<<64, 512, 0, stream>>>(WTf, ain, aout, b, h, c, out, t);
    }
}